// Round 4
// baseline (338.690 us; speedup 1.0000x reference)
//
#include <hip/hip_runtime.h>
#include <math.h>

#define B_    32
#define H_    28
#define W_    28
#define C_    768
#define D_    64
#define EMB_  64
#define HW_   (H_ * W_)
#define NPOS  (B_ * HW_)          // 25088
#define CWROWS (D_ * D_ * 9)      // 36864

__device__ __forceinline__ float qgelu(float v) {
    return v / (1.f + __expf(-1.702f * v));
}
__device__ __forceinline__ float relu(float v) { return fmaxf(v, 0.f); }

// ---------------- Stage 0: 32x32 tiled transpose ----------------
// dst[c][colOff + r] = src[r][c]; dst row stride dstStride. Block (32,8).
__global__ void k_tr(const float* __restrict__ src, int R, int C,
                     float* __restrict__ dst, int dstStride, int colOff)
{
    __shared__ float tile[32][33];
    const int c0 = blockIdx.x * 32, r0 = blockIdx.y * 32;
    const int tx = threadIdx.x, ty = threadIdx.y;
    #pragma unroll
    for (int i = 0; i < 4; ++i)
        tile[ty + 8 * i][tx] = src[(size_t)(r0 + ty + 8 * i) * C + c0 + tx];
    __syncthreads();
    #pragma unroll
    for (int i = 0; i < 4; ++i)
        dst[(size_t)(c0 + ty + 8 * i) * dstStride + colOff + r0 + tx] = tile[tx][ty + 8 * i];
}

// ---------------- Stage 1+4: tiled GEMM, N=128 (64 relu-h | 64 qgelu-down) ----------------
// x_t chunk-padded k-major: float offset (k,m) = k*192 + (m>>3)*12 + (m&7)
#define XT_OFF(k, m) ((k) * 192 + ((m) >> 3) * 12 + ((m) & 7))

__global__ __launch_bounds__(256, 4)
void k_gemm_md(const float* __restrict__ x, const float* __restrict__ wT,
               const float* __restrict__ b1, const float* __restrict__ db,
               float* __restrict__ hbuf, float* __restrict__ xact)
{
    __shared__ float xt[16 * 192];    // 12 KB
    __shared__ float wt[16][128];     //  8 KB
    const int t  = threadIdx.x;
    const int tm = t & 15, tn = t >> 4;
    const int bm = blockIdx.x;        // 196 blocks, Mt=128

    float acc[8][8];
    #pragma unroll
    for (int i = 0; i < 8; ++i)
        #pragma unroll
        for (int j = 0; j < 8; ++j) acc[i][j] = 0.f;

    for (int k0 = 0; k0 < C_; k0 += 16) {
        __syncthreads();
        // stage x tile [128 rows][16 k] -> transposed chunk-padded LDS
        #pragma unroll
        for (int s = 0; s < 2; ++s) {
            const int j = s * 256 + t;
            const int row = j >> 2, c4 = j & 3;
            float4 v = *(const float4*)(x + (size_t)(bm * 128 + row) * C_ + k0 + c4 * 4);
            xt[XT_OFF(c4 * 4 + 0, row)] = v.x;
            xt[XT_OFF(c4 * 4 + 1, row)] = v.y;
            xt[XT_OFF(c4 * 4 + 2, row)] = v.z;
            xt[XT_OFF(c4 * 4 + 3, row)] = v.w;
        }
        // stage w tile (wT already k-major): contiguous copy
        #pragma unroll
        for (int s = 0; s < 2; ++s) {
            const int j = s * 256 + t;
            const int k = j >> 5, c4 = j & 31;
            *(float4*)&wt[k][c4 * 4] = *(const float4*)(wT + (size_t)(k0 + k) * 128 + c4 * 4);
        }
        __syncthreads();
        #pragma unroll
        for (int k = 0; k < 16; ++k) {
            float a[8], b[8];
            *(float4*)&a[0] = *(const float4*)&xt[XT_OFF(k, tm * 8)];
            *(float4*)&a[4] = *(const float4*)&xt[XT_OFF(k, tm * 8 + 4)];
            *(float4*)&b[0] = *(const float4*)&wt[k][tn * 8];
            *(float4*)&b[4] = *(const float4*)&wt[k][tn * 8 + 4];
            #pragma unroll
            for (int i = 0; i < 8; ++i)
                #pragma unroll
                for (int j = 0; j < 8; ++j)
                    acc[i][j] = fmaf(a[i], b[j], acc[i][j]);
        }
    }

    const int pos0 = bm * 128 + tm * 8;
    if (tn < 8) {                     // meta1 half: relu(acc + b1) -> hbuf
        const int c = tn * 8;
        float4 bb0 = *(const float4*)(b1 + c);
        float4 bb1 = *(const float4*)(b1 + c + 4);
        #pragma unroll
        for (int i = 0; i < 8; ++i) {
            float4 v0 = make_float4(relu(acc[i][0] + bb0.x), relu(acc[i][1] + bb0.y),
                                    relu(acc[i][2] + bb0.z), relu(acc[i][3] + bb0.w));
            float4 v1 = make_float4(relu(acc[i][4] + bb1.x), relu(acc[i][5] + bb1.y),
                                    relu(acc[i][6] + bb1.z), relu(acc[i][7] + bb1.w));
            float* o = hbuf + (size_t)(pos0 + i) * 64 + c;
            *(float4*)o = v0;
            *(float4*)(o + 4) = v1;
        }
    } else {                          // down half: qgelu(acc + db) -> xact
        const int c = (tn - 8) * 8;
        float4 bb0 = *(const float4*)(db + c);
        float4 bb1 = *(const float4*)(db + c + 4);
        #pragma unroll
        for (int i = 0; i < 8; ++i) {
            float4 v0 = make_float4(qgelu(acc[i][0] + bb0.x), qgelu(acc[i][1] + bb0.y),
                                    qgelu(acc[i][2] + bb0.z), qgelu(acc[i][3] + bb0.w));
            float4 v1 = make_float4(qgelu(acc[i][4] + bb1.x), qgelu(acc[i][5] + bb1.y),
                                    qgelu(acc[i][6] + bb1.z), qgelu(acc[i][7] + bb1.w));
            float* o = xact + (size_t)(pos0 + i) * 64 + c;
            *(float4*)o = v0;
            *(float4*)(o + 4) = v1;
        }
    }
}

// ---------------- Stage 2: spatial mean + meta2 (commuted past mean) ----------------
__global__ void k_reduce(const float* __restrict__ hbuf,
                         const float* __restrict__ w2, const float* __restrict__ b2,
                         float* __restrict__ prompt)
{
    __shared__ float part[4][EMB_];
    __shared__ float hm[EMB_];
    const int b     = blockIdx.x;
    const int lane  = threadIdx.x & 63;
    const int chunk = threadIdx.x >> 6;
    float acc = 0.f;
    for (int i = chunk; i < HW_; i += 4)
        acc += hbuf[((size_t)b * HW_ + i) * EMB_ + lane];
    part[chunk][lane] = acc;
    __syncthreads();
    if (threadIdx.x < EMB_) {
        float s = part[0][threadIdx.x] + part[1][threadIdx.x]
                + part[2][threadIdx.x] + part[3][threadIdx.x];
        hm[threadIdx.x] = s * (1.f / HW_);
    }
    __syncthreads();
    if (threadIdx.x < EMB_) {
        const int e = threadIdx.x;
        const float* w2r = w2 + (size_t)e * EMB_;
        float a0 = 0.f, a1 = 0.f, a2 = 0.f, a3 = 0.f;
        #pragma unroll
        for (int i = 0; i < EMB_; i += 4) {
            a0 = fmaf(hm[i + 0], w2r[i + 0], a0);
            a1 = fmaf(hm[i + 1], w2r[i + 1], a1);
            a2 = fmaf(hm[i + 2], w2r[i + 2], a2);
            a3 = fmaf(hm[i + 3], w2r[i + 3], a3);
        }
        prompt[b * EMB_ + e] = (a0 + a1) + (a2 + a3) + b2[e];
    }
}

// ---------------- Stage 3: hypernet -> conv weights [b][tap][din][dout] ----------------
__global__ void k_hyper(const float* __restrict__ prompt, const float* __restrict__ layer_emb,
                        const float* __restrict__ hyper_w, const float* __restrict__ hyper_b,
                        float* __restrict__ cw2)
{
    __shared__ float fused[B_][EMB_];
    const int tid = threadIdx.x;
    for (int i = tid; i < B_ * EMB_; i += 256) {
        int e = i & (EMB_ - 1);
        fused[i >> 6][e] = layer_emb[e] + prompt[i];
    }
    __syncthreads();

    const int f    = blockIdx.x * 256 + tid;   // 0..36863
    const int dout = f & 63;
    const int din  = (f >> 6) & 63;
    const int tap  = f >> 12;
    const int r    = (dout * 64 + din) * 9 + tap;

    float wrow[EMB_];
    const float4* hw4 = (const float4*)(hyper_w + (size_t)r * EMB_);
    #pragma unroll
    for (int i = 0; i < EMB_ / 4; ++i) {
        float4 v = hw4[i];
        wrow[i*4+0] = v.x; wrow[i*4+1] = v.y; wrow[i*4+2] = v.z; wrow[i*4+3] = v.w;
    }
    const float hb = hyper_b[r];

    const int b0 = blockIdx.y * 8;
    for (int b = b0; b < b0 + 8; ++b) {
        float a0 = 0.f, a1 = 0.f, a2 = 0.f, a3 = 0.f;
        #pragma unroll
        for (int i = 0; i < EMB_; i += 4) {
            a0 = fmaf(fused[b][i+0], wrow[i+0], a0);
            a1 = fmaf(fused[b][i+1], wrow[i+1], a1);
            a2 = fmaf(fused[b][i+2], wrow[i+2], a2);
            a3 = fmaf(fused[b][i+3], wrow[i+3], a3);
        }
        cw2[(size_t)b * CWROWS + f] = (a0 + a1) + (a2 + a3) + hb;
    }
}

// ---------------- Stage 5: per-sample 3x3 conv + QuickGELU ----------------
__global__ void k_conv(const float* __restrict__ xact, const float* __restrict__ cw2,
                       float* __restrict__ yact)
{
    __shared__ float xs[W_ * D_];
    __shared__ float ws[3][D_][D_];
    const int b    = blockIdx.x / H_;
    const int h    = blockIdx.x % H_;
    const int tid  = threadIdx.x;
    const int wave = tid >> 6;
    const int lane = tid & 63;
    const int wstart = wave * 7;

    float acc[7];
    #pragma unroll
    for (int p = 0; p < 7; ++p) acc[p] = 0.f;

    for (int kh = 0; kh < 3; ++kh) {
        const int hh = h + kh - 1;
        const bool valid = (hh >= 0) && (hh < H_);
        __syncthreads();
        if (valid) {
            const float4* src = (const float4*)(cw2 + (size_t)b * CWROWS + (size_t)kh * 3 * D_ * D_);
            float4* dst = (float4*)ws;
            for (int i = tid; i < 3 * D_ * D_ / 4; i += 256) dst[i] = src[i];
            const float4* xsrc = (const float4*)(xact + ((size_t)(b * H_ + hh) * W_) * D_);
            float4* xdst = (float4*)xs;
            for (int i = tid; i < W_ * D_ / 4; i += 256) xdst[i] = xsrc[i];
        }
        __syncthreads();
        if (!valid) continue;

        #pragma unroll 1
        for (int dq = 0; dq < D_ / 4; ++dq) {
            float4 xv[9];
            #pragma unroll
            for (int i = 0; i < 9; ++i) {
                int col = wstart + i - 1;
                if (col >= 0 && col < W_)
                    xv[i] = *(const float4*)&xs[col * D_ + dq * 4];
                else
                    xv[i] = make_float4(0.f, 0.f, 0.f, 0.f);
            }
            float wr[3][4];
            #pragma unroll
            for (int kw = 0; kw < 3; ++kw)
                #pragma unroll
                for (int j = 0; j < 4; ++j)
                    wr[kw][j] = ws[kw][dq * 4 + j][lane];
            #pragma unroll
            for (int p = 0; p < 7; ++p) {
                #pragma unroll
                for (int kw = 0; kw < 3; ++kw) {
                    const float* xq = (const float*)&xv[p + kw];
                    acc[p] = fmaf(xq[0], wr[kw][0], acc[p]);
                    acc[p] = fmaf(xq[1], wr[kw][1], acc[p]);
                    acc[p] = fmaf(xq[2], wr[kw][2], acc[p]);
                    acc[p] = fmaf(xq[3], wr[kw][3], acc[p]);
                }
            }
        }
    }

    const size_t base = ((size_t)(b * H_ + h) * W_ + wstart) * D_;
    #pragma unroll
    for (int p = 0; p < 7; ++p)
        yact[base + (size_t)p * D_ + lane] = qgelu(acc[p]);
}

// ---------------- Stage 6: adapter-up, tiled GEMM M=25088 N=768 K=64 ----------------
__global__ void k_up(const float* __restrict__ yact, const float* __restrict__ uw,
                     const float* __restrict__ ub, float* __restrict__ out)
{
    __shared__ float yt[64][67];    // padded: a-reads 2-way max
    __shared__ float wt[128][65];   // padded: b-reads conflict-free broadcasts
    const int t = threadIdx.x, tm = t & 15, tn = t >> 4;
    const int bm = blockIdx.x;      // 392 blocks, Mt=64

    // stage y tile once (scalar stores due to pad)
    #pragma unroll
    for (int s = 0; s < 4; ++s) {
        const int j = s * 256 + t;
        const int row = j >> 4, c4 = j & 15;
        float4 v = *(const float4*)(yact + (size_t)(bm * 64 + row) * 64 + c4 * 4);
        yt[row][c4 * 4 + 0] = v.x; yt[row][c4 * 4 + 1] = v.y;
        yt[row][c4 * 4 + 2] = v.z; yt[row][c4 * 4 + 3] = v.w;
    }

    for (int nc = 0; nc < 6; ++nc) {
        __syncthreads();
        // stage weight chunk: 128 rows (n) x 64 (k), direct copy of up_w rows
        #pragma unroll
        for (int s = 0; s < 8; ++s) {
            const int j = s * 256 + t;
            const int row = j >> 4, c4 = j & 15;
            float4 v = *(const float4*)(uw + (size_t)(nc * 128 + row) * 64 + c4 * 4);
            wt[row][c4 * 4 + 0] = v.x; wt[row][c4 * 4 + 1] = v.y;
            wt[row][c4 * 4 + 2] = v.z; wt[row][c4 * 4 + 3] = v.w;
        }
        __syncthreads();

        float acc[4][8];
        #pragma unroll
        for (int i = 0; i < 4; ++i)
            #pragma unroll
            for (int j = 0; j < 8; ++j) acc[i][j] = 0.f;

        for (int k = 0; k < D_; ++k) {
            float a[4], b[8];
            #pragma unroll
            for (int i = 0; i < 4; ++i) a[i] = yt[tm * 4 + i][k];
            #pragma unroll
            for (int j = 0; j < 8; ++j) b[j] = wt[tn * 8 + j][k];
            #pragma unroll
            for (int i = 0; i < 4; ++i)
                #pragma unroll
                for (int j = 0; j < 8; ++j)
                    acc[i][j] = fmaf(a[i], b[j], acc[i][j]);
        }

        const int c = nc * 128 + tn * 8;
        float4 u0 = *(const float4*)(ub + c);
        float4 u1 = *(const float4*)(ub + c + 4);
        #pragma unroll
        for (int i = 0; i < 4; ++i) {
            const int pos = bm * 64 + tm * 4 + i;
            float* o = out + (size_t)pos * C_ + c;
            *(float4*)o = make_float4(acc[i][0] + u0.x, acc[i][1] + u0.y,
                                      acc[i][2] + u0.z, acc[i][3] + u0.w);
            *(float4*)(o + 4) = make_float4(acc[i][4] + u1.x, acc[i][5] + u1.y,
                                            acc[i][6] + u1.z, acc[i][7] + u1.w);
        }
    }
}

extern "C" void kernel_launch(void* const* d_in, const int* in_sizes, int n_in,
                              void* d_out, int out_size, void* d_ws, size_t ws_size,
                              hipStream_t stream) {
    const float* x         = (const float*)d_in[0];
    const float* meta_w1   = (const float*)d_in[1];
    const float* meta_b1   = (const float*)d_in[2];
    const float* meta_w2   = (const float*)d_in[3];
    const float* meta_b2   = (const float*)d_in[4];
    const float* layer_emb = (const float*)d_in[5];
    const float* hyper_w   = (const float*)d_in[6];
    const float* hyper_b   = (const float*)d_in[7];
    const float* down_w    = (const float*)d_in[8];
    const float* down_b    = (const float*)d_in[9];
    const float* up_w      = (const float*)d_in[10];
    const float* up_b      = (const float*)d_in[11];
    float* out = (float*)d_out;

    // ws layout (floats). wT and cw2 share a region: wT is dead before k_hyper
    // writes cw2. yact aliases hbuf (hbuf dead after k_reduce).
    float* ws     = (float*)d_ws;
    float* hbuf   = ws;                               // NPOS*64
    float* yact   = hbuf;                             // alias
    float* xact   = ws + (size_t)NPOS * 64;           // NPOS*64
    float* prompt = xact + (size_t)NPOS * 64;         // 2048
    float* wT     = prompt + B_ * EMB_;               // 768*128 (then clobbered by cw2)
    float* cw2    = wT;                               // B*36864

    // transpose w1 -> wT cols 0..63, down_w -> wT cols 64..127
    dim3 trb(32, 8);
    k_tr<<<dim3(C_ / 32, EMB_ / 32), trb, 0, stream>>>(meta_w1, EMB_, C_, wT, 128, 0);
    k_tr<<<dim3(C_ / 32, D_ / 32),   trb, 0, stream>>>(down_w,  D_,   C_, wT, 128, 64);

    k_gemm_md<<<NPOS / 128, 256, 0, stream>>>(x, wT, meta_b1, down_b, hbuf, xact);
    k_reduce<<<B_, 256, 0, stream>>>(hbuf, meta_w2, meta_b2, prompt);
    dim3 hgrid(CWROWS / 256, B_ / 8);
    k_hyper<<<hgrid, 256, 0, stream>>>(prompt, layer_emb, hyper_w, hyper_b, cw2);
    k_conv<<<B_ * H_, 256, 0, stream>>>(xact, cw2, yact);
    k_up<<<NPOS / 64, 256, 0, stream>>>(yact, up_w, up_b, out);
}

// Round 5
// 193.116 us; speedup vs baseline: 1.7538x; 1.7538x over previous
//
#include <hip/hip_runtime.h>
#include <math.h>

#define B_    32
#define H_    28
#define W_    28
#define C_    768
#define D_    64
#define EMB_  64
#define HW_   (H_ * W_)
#define NPOS  (B_ * HW_)          // 25088
#define CWROWS (D_ * D_ * 9)      // 36864

typedef __attribute__((ext_vector_type(8))) short bf16x8;
typedef __attribute__((ext_vector_type(4))) float f32x4;

__device__ __forceinline__ float qgelu(float v) {
    return v / (1.f + __expf(-1.702f * v));
}
__device__ __forceinline__ float relu(float v) { return fmaxf(v, 0.f); }

// fp32 -> bf16 RTNE
__device__ __forceinline__ ushort f2bf(float f) {
    union { float f; unsigned u; } v; v.f = f;
    return (ushort)((v.u + 0x7fffu + ((v.u >> 16) & 1u)) >> 16);
}

// XOR-swizzled LDS tile address: tile rows are 128 B (64 bf16), byte offset
// within row is kbyte ^ ((row&7)<<4) -> every consecutive-8-lane b128 group
// covers all 8 bank-groups (G4 / T2).
__device__ __forceinline__ void* swz(void* base, int row, int kbyte) {
    return (void*)((char*)base + row * 128 + (kbyte ^ ((row & 7) << 4)));
}

// ---------------- Stage 0: weight convert fp32 -> bf16 ----------------
// wcat[128][768] = [w1 rows; down_w rows] (B-operand layout for k_gemm_md)
// wup[768][64]   = up_w rows              (B-operand layout for k_up)
__global__ void k_cvt(const float* __restrict__ w1, const float* __restrict__ dw,
                      const float* __restrict__ uw,
                      ushort* __restrict__ wcat, ushort* __restrict__ wup)
{
    const int f = (blockIdx.x * 256 + threadIdx.x) * 4;   // 147456 total
    const float* src;
    ushort* dst;
    if (f < 49152)      { src = w1 + f;           dst = wcat + f; }
    else if (f < 98304) { src = dw + (f - 49152); dst = wcat + f; }
    else                { src = uw + (f - 98304); dst = wup + (f - 98304); }
    float4 v = *(const float4*)src;
    union { ushort u[4]; uint2 p; } o;
    o.u[0] = f2bf(v.x); o.u[1] = f2bf(v.y); o.u[2] = f2bf(v.z); o.u[3] = f2bf(v.w);
    *(uint2*)dst = o.p;
}

// ---------------- Stage 1+4: MFMA GEMM  M=25088 N=128 K=768 ----------------
// 8 waves, M-tile 64, wave owns n = wid*16 + (lane&15); waves 0-3 -> hbuf
// (relu), 4-7 -> xact (qgelu).
__global__ __launch_bounds__(512)
void k_gemm_md(const float* __restrict__ x, const ushort* __restrict__ wcat,
               const float* __restrict__ b1, const float* __restrict__ db,
               float* __restrict__ hbuf, float* __restrict__ xact)
{
    __shared__ ushort As[64 * 64];    //  8 KB, [m][k] swizzled
    __shared__ ushort Bs[128 * 64];   // 16 KB, [n][k] swizzled
    const int t = threadIdx.x;
    const int wid = t >> 6, lane = t & 63;
    const int lo = lane & 15, hi = lane >> 4;
    const int bm = blockIdx.x;        // 392

    f32x4 acc[4] = {};

    const int arow = t >> 3, akseg = t & 7;
    const float* asrc = x + (size_t)(bm * 64 + arow) * C_ + akseg * 8;

    for (int k0 = 0; k0 < C_; k0 += 64) {
        __syncthreads();
        {   // stage A: 64 rows x 64 k, fp32->bf16, one b128 per thread
            float4 v0 = *(const float4*)(asrc + k0);
            float4 v1 = *(const float4*)(asrc + k0 + 4);
            union { ushort u[8]; float4 v; } tmp;
            tmp.u[0] = f2bf(v0.x); tmp.u[1] = f2bf(v0.y);
            tmp.u[2] = f2bf(v0.z); tmp.u[3] = f2bf(v0.w);
            tmp.u[4] = f2bf(v1.x); tmp.u[5] = f2bf(v1.y);
            tmp.u[6] = f2bf(v1.z); tmp.u[7] = f2bf(v1.w);
            *(float4*)swz(As, arow, akseg * 16) = tmp.v;
        }
        #pragma unroll
        for (int s = 0; s < 2; ++s) {   // stage B: 128 rows x 64 k bf16 copy
            int j = s * 512 + t;
            int n = j >> 3, kseg = j & 7;
            *(float4*)swz(Bs, n, kseg * 16) =
                *(const float4*)(wcat + (size_t)n * C_ + k0 + kseg * 8);
        }
        __syncthreads();
        #pragma unroll
        for (int ks = 0; ks < 2; ++ks) {
            bf16x8 b = *(const bf16x8*)swz(Bs, wid * 16 + lo, ks * 64 + hi * 16);
            #pragma unroll
            for (int i = 0; i < 4; ++i) {
                bf16x8 a = *(const bf16x8*)swz(As, i * 16 + lo, ks * 64 + hi * 16);
                acc[i] = __builtin_amdgcn_mfma_f32_16x16x32_bf16(a, b, acc[i], 0, 0, 0);
            }
        }
    }

    const int n = wid * 16 + lo;      // 0..127
    if (wid < 4) {
        const float bias = b1[n];
        #pragma unroll
        for (int i = 0; i < 4; ++i)
            #pragma unroll
            for (int r = 0; r < 4; ++r) {
                int pos = bm * 64 + i * 16 + hi * 4 + r;
                hbuf[(size_t)pos * 64 + n] = relu(acc[i][r] + bias);
            }
    } else {
        const float bias = db[n - 64];
        #pragma unroll
        for (int i = 0; i < 4; ++i)
            #pragma unroll
            for (int r = 0; r < 4; ++r) {
                int pos = bm * 64 + i * 16 + hi * 4 + r;
                xact[(size_t)pos * 64 + (n - 64)] = qgelu(acc[i][r] + bias);
            }
    }
}

// ---------------- Stage 2: spatial mean + meta2 (commuted past mean) ----------------
__global__ void k_reduce(const float* __restrict__ hbuf,
                         const float* __restrict__ w2, const float* __restrict__ b2,
                         float* __restrict__ prompt)
{
    __shared__ float part[4][EMB_];
    __shared__ float hm[EMB_];
    const int b     = blockIdx.x;
    const int lane  = threadIdx.x & 63;
    const int chunk = threadIdx.x >> 6;
    float acc = 0.f;
    for (int i = chunk; i < HW_; i += 4)
        acc += hbuf[((size_t)b * HW_ + i) * EMB_ + lane];
    part[chunk][lane] = acc;
    __syncthreads();
    if (threadIdx.x < EMB_) {
        float s = part[0][threadIdx.x] + part[1][threadIdx.x]
                + part[2][threadIdx.x] + part[3][threadIdx.x];
        hm[threadIdx.x] = s * (1.f / HW_);
    }
    __syncthreads();
    if (threadIdx.x < EMB_) {
        const int e = threadIdx.x;
        const float* w2r = w2 + (size_t)e * EMB_;
        float a0 = 0.f, a1 = 0.f, a2 = 0.f, a3 = 0.f;
        #pragma unroll
        for (int i = 0; i < EMB_; i += 4) {
            a0 = fmaf(hm[i + 0], w2r[i + 0], a0);
            a1 = fmaf(hm[i + 1], w2r[i + 1], a1);
            a2 = fmaf(hm[i + 2], w2r[i + 2], a2);
            a3 = fmaf(hm[i + 3], w2r[i + 3], a3);
        }
        prompt[b * EMB_ + e] = (a0 + a1) + (a2 + a3) + b2[e];
    }
}

// ---------------- Stage 3: hypernet -> conv weights [b][tap][din][dout] ----------------
__global__ void k_hyper(const float* __restrict__ prompt, const float* __restrict__ layer_emb,
                        const float* __restrict__ hyper_w, const float* __restrict__ hyper_b,
                        float* __restrict__ cw2)
{
    __shared__ float fused[B_][EMB_];
    const int tid = threadIdx.x;
    for (int i = tid; i < B_ * EMB_; i += 256) {
        int e = i & (EMB_ - 1);
        fused[i >> 6][e] = layer_emb[e] + prompt[i];
    }
    __syncthreads();

    const int f    = blockIdx.x * 256 + tid;
    const int dout = f & 63;
    const int din  = (f >> 6) & 63;
    const int tap  = f >> 12;
    const int r    = (dout * 64 + din) * 9 + tap;

    float wrow[EMB_];
    const float4* hw4 = (const float4*)(hyper_w + (size_t)r * EMB_);
    #pragma unroll
    for (int i = 0; i < EMB_ / 4; ++i) {
        float4 v = hw4[i];
        wrow[i*4+0] = v.x; wrow[i*4+1] = v.y; wrow[i*4+2] = v.z; wrow[i*4+3] = v.w;
    }
    const float hb = hyper_b[r];

    const int b0 = blockIdx.y * 8;
    for (int b = b0; b < b0 + 8; ++b) {
        float a0 = 0.f, a1 = 0.f, a2 = 0.f, a3 = 0.f;
        #pragma unroll
        for (int i = 0; i < EMB_; i += 4) {
            a0 = fmaf(fused[b][i+0], wrow[i+0], a0);
            a1 = fmaf(fused[b][i+1], wrow[i+1], a1);
            a2 = fmaf(fused[b][i+2], wrow[i+2], a2);
            a3 = fmaf(fused[b][i+3], wrow[i+3], a3);
        }
        cw2[(size_t)b * CWROWS + f] = (a0 + a1) + (a2 + a3) + hb;
    }
}

// ---------------- Stage 5: per-sample 3x3 conv + QuickGELU (bf16 out) ----------------
__global__ void k_conv(const float* __restrict__ xact, const float* __restrict__ cw2,
                       ushort* __restrict__ yact)
{
    __shared__ float xs[W_ * D_];
    __shared__ float ws[3][D_][D_];
    const int b    = blockIdx.x / H_;
    const int h    = blockIdx.x % H_;
    const int tid  = threadIdx.x;
    const int wave = tid >> 6;
    const int lane = tid & 63;
    const int wstart = wave * 7;

    float acc[7];
    #pragma unroll
    for (int p = 0; p < 7; ++p) acc[p] = 0.f;

    for (int kh = 0; kh < 3; ++kh) {
        const int hh = h + kh - 1;
        const bool valid = (hh >= 0) && (hh < H_);
        __syncthreads();
        if (valid) {
            const float4* src = (const float4*)(cw2 + (size_t)b * CWROWS + (size_t)kh * 3 * D_ * D_);
            float4* dst = (float4*)ws;
            for (int i = tid; i < 3 * D_ * D_ / 4; i += 256) dst[i] = src[i];
            const float4* xsrc = (const float4*)(xact + ((size_t)(b * H_ + hh) * W_) * D_);
            float4* xdst = (float4*)xs;
            for (int i = tid; i < W_ * D_ / 4; i += 256) xdst[i] = xsrc[i];
        }
        __syncthreads();
        if (!valid) continue;

        #pragma unroll 1
        for (int dq = 0; dq < D_ / 4; ++dq) {
            float4 xv[9];
            #pragma unroll
            for (int i = 0; i < 9; ++i) {
                int col = wstart + i - 1;
                if (col >= 0 && col < W_)
                    xv[i] = *(const float4*)&xs[col * D_ + dq * 4];
                else
                    xv[i] = make_float4(0.f, 0.f, 0.f, 0.f);
            }
            float wr[3][4];
            #pragma unroll
            for (int kw = 0; kw < 3; ++kw)
                #pragma unroll
                for (int j = 0; j < 4; ++j)
                    wr[kw][j] = ws[kw][dq * 4 + j][lane];
            #pragma unroll
            for (int p = 0; p < 7; ++p) {
                #pragma unroll
                for (int kw = 0; kw < 3; ++kw) {
                    const float* xq = (const float*)&xv[p + kw];
                    acc[p] = fmaf(xq[0], wr[kw][0], acc[p]);
                    acc[p] = fmaf(xq[1], wr[kw][1], acc[p]);
                    acc[p] = fmaf(xq[2], wr[kw][2], acc[p]);
                    acc[p] = fmaf(xq[3], wr[kw][3], acc[p]);
                }
            }
        }
    }

    const size_t base = ((size_t)(b * H_ + h) * W_ + wstart) * D_;
    #pragma unroll
    for (int p = 0; p < 7; ++p)
        yact[base + (size_t)p * D_ + lane] = f2bf(qgelu(acc[p]));
}

// ---------------- Stage 6: MFMA GEMM  M=25088 N=768 K=64 ----------------
__global__ __launch_bounds__(512)
void k_up(const ushort* __restrict__ yact, const ushort* __restrict__ wup,
          const float* __restrict__ ub, float* __restrict__ out)
{
    __shared__ ushort As[64 * 64];    //  8 KB
    __shared__ ushort Bs[256 * 64];   // 32 KB
    const int t = threadIdx.x;
    const int wid = t >> 6, lane = t & 63;
    const int lo = lane & 15, hi = lane >> 4;
    const int bm = blockIdx.x;        // 392

    {   // stage A once (yact already bf16): one b128 per thread
        int row = t >> 3, kseg = t & 7;
        *(float4*)swz(As, row, kseg * 16) =
            *(const float4*)(yact + (size_t)(bm * 64 + row) * 64 + kseg * 8);
    }

    for (int nc = 0; nc < 3; ++nc) {
        __syncthreads();
        #pragma unroll
        for (int s = 0; s < 4; ++s) {   // stage B: 256 n-rows x 64 k
            int j = s * 512 + t;
            int n = j >> 3, kseg = j & 7;
            *(float4*)swz(Bs, n, kseg * 16) =
                *(const float4*)(wup + (size_t)(nc * 256 + n) * 64 + kseg * 8);
        }
        __syncthreads();

        f32x4 acc[4][2] = {};
        #pragma unroll
        for (int ks = 0; ks < 2; ++ks) {
            bf16x8 a[4], b[2];
            #pragma unroll
            for (int i = 0; i < 4; ++i)
                a[i] = *(const bf16x8*)swz(As, i * 16 + lo, ks * 64 + hi * 16);
            #pragma unroll
            for (int j = 0; j < 2; ++j)
                b[j] = *(const bf16x8*)swz(Bs, wid * 32 + j * 16 + lo, ks * 64 + hi * 16);
            #pragma unroll
            for (int i = 0; i < 4; ++i)
                #pragma unroll
                for (int j = 0; j < 2; ++j)
                    acc[i][j] = __builtin_amdgcn_mfma_f32_16x16x32_bf16(a[i], b[j], acc[i][j], 0, 0, 0);
        }

        #pragma unroll
        for (int j = 0; j < 2; ++j) {
            const int n = nc * 256 + wid * 32 + j * 16 + lo;
            const float bias = ub[n];
            #pragma unroll
            for (int i = 0; i < 4; ++i)
                #pragma unroll
                for (int r = 0; r < 4; ++r) {
                    int pos = bm * 64 + i * 16 + hi * 4 + r;
                    out[(size_t)pos * C_ + n] = acc[i][j][r] + bias;
                }
        }
    }
}

extern "C" void kernel_launch(void* const* d_in, const int* in_sizes, int n_in,
                              void* d_out, int out_size, void* d_ws, size_t ws_size,
                              hipStream_t stream) {
    const float* x         = (const float*)d_in[0];
    const float* meta_w1   = (const float*)d_in[1];
    const float* meta_b1   = (const float*)d_in[2];
    const float* meta_w2   = (const float*)d_in[3];
    const float* meta_b2   = (const float*)d_in[4];
    const float* layer_emb = (const float*)d_in[5];
    const float* hyper_w   = (const float*)d_in[6];
    const float* hyper_b   = (const float*)d_in[7];
    const float* down_w    = (const float*)d_in[8];
    const float* down_b    = (const float*)d_in[9];
    const float* up_w      = (const float*)d_in[10];
    const float* up_b      = (const float*)d_in[11];
    float* out = (float*)d_out;

    // ws layout (floats). yact (bf16) aliases hbuf: hbuf dead after k_reduce,
    // k_conv writes yact afterwards (stream-serialized).
    float*  ws     = (float*)d_ws;
    float*  hbuf   = ws;                               // NPOS*64 f32
    ushort* yact   = (ushort*)hbuf;                    // alias, NPOS*64 bf16
    float*  xact   = ws + (size_t)NPOS * 64;           // NPOS*64 f32
    float*  prompt = xact + (size_t)NPOS * 64;         // 2048
    float*  cw2    = prompt + B_ * EMB_;               // 32*36864
    ushort* wcat   = (ushort*)(cw2 + (size_t)B_ * CWROWS);  // 128*768 bf16
    ushort* wup    = wcat + 128 * C_;                  // 768*64 bf16

    k_cvt<<<144, 256, 0, stream>>>(meta_w1, down_w, up_w, wcat, wup);
    k_gemm_md<<<NPOS / 64, 512, 0, stream>>>(x, wcat, meta_b1, down_b, hbuf, xact);
    k_reduce<<<B_, 256, 0, stream>>>(hbuf, meta_w2, meta_b2, prompt);
    dim3 hgrid(CWROWS / 256, B_ / 8);
    k_hyper<<<hgrid, 256, 0, stream>>>(prompt, layer_emb, hyper_w, hyper_b, cw2);
    k_conv<<<B_ * H_, 256, 0, stream>>>(xact, cw2, yact);
    k_up<<<NPOS / 64, 512, 0, stream>>>(yact, wup, up_b, out);
}

// Round 6
// 110.265 us; speedup vs baseline: 3.0716x; 1.7514x over previous
//
#include <hip/hip_runtime.h>
#include <math.h>

#define B_    32
#define H_    28
#define W_    28
#define C_    768
#define D_    64
#define EMB_  64
#define HW_   (H_ * W_)
#define NPOS  (B_ * HW_)          // 25088
#define CWROWS (D_ * D_ * 9)      // 36864

typedef __attribute__((ext_vector_type(8))) short bf16x8;
typedef __attribute__((ext_vector_type(4))) float f32x4;

__device__ __forceinline__ float qgelu(float v) {
    return v / (1.f + __expf(-1.702f * v));
}
__device__ __forceinline__ float relu(float v) { return fmaxf(v, 0.f); }

// fp32 -> bf16 RTNE
__device__ __forceinline__ ushort f2bf(float f) {
    union { float f; unsigned u; } v; v.f = f;
    return (ushort)((v.u + 0x7fffu + ((v.u >> 16) & 1u)) >> 16);
}

// XOR-swizzled LDS tile address: rows are 128 B (64 bf16); byte offset within
// row is kbyte ^ ((row&7)<<4) -> b128 reads across 16 rows are <=2-way (free).
__device__ __forceinline__ void* swz(void* base, int row, int kbyte) {
    return (void*)((char*)base + row * 128 + (kbyte ^ ((row & 7) << 4)));
}

// ---------------- Stage 0: weight convert fp32 -> bf16 ----------------
__global__ void k_cvt(const float* __restrict__ w1, const float* __restrict__ dw,
                      const float* __restrict__ uw,
                      ushort* __restrict__ wcat, ushort* __restrict__ wup)
{
    const int f = (blockIdx.x * 256 + threadIdx.x) * 4;   // 147456 total
    const float* src;
    ushort* dst;
    if (f < 49152)      { src = w1 + f;           dst = wcat + f; }
    else if (f < 98304) { src = dw + (f - 49152); dst = wcat + f; }
    else                { src = uw + (f - 98304); dst = wup + (f - 98304); }
    float4 v = *(const float4*)src;
    union { ushort u[4]; uint2 p; } o;
    o.u[0] = f2bf(v.x); o.u[1] = f2bf(v.y); o.u[2] = f2bf(v.z); o.u[3] = f2bf(v.w);
    *(uint2*)dst = o.p;
}

// ---------------- Stage 1+4: MFMA GEMM  M=25088 N=128 K=768 ----------------
// waves 0-3 -> hbuf f32 (relu), waves 4-7 -> xact bf16 (qgelu)
__global__ __launch_bounds__(512)
void k_gemm_md(const float* __restrict__ x, const ushort* __restrict__ wcat,
               const float* __restrict__ b1, const float* __restrict__ db,
               float* __restrict__ hbuf, ushort* __restrict__ xact)
{
    __shared__ ushort As[64 * 64];    //  8 KB, [m][k] swizzled
    __shared__ ushort Bs[128 * 64];   // 16 KB, [n][k] swizzled
    const int t = threadIdx.x;
    const int wid = t >> 6, lane = t & 63;
    const int lo = lane & 15, hi = lane >> 4;
    const int bm = blockIdx.x;        // 392

    f32x4 acc[4] = {};

    const int arow = t >> 3, akseg = t & 7;
    const float* asrc = x + (size_t)(bm * 64 + arow) * C_ + akseg * 8;

    for (int k0 = 0; k0 < C_; k0 += 64) {
        __syncthreads();
        {   // stage A: 64 rows x 64 k, fp32->bf16, one b128 per thread
            float4 v0 = *(const float4*)(asrc + k0);
            float4 v1 = *(const float4*)(asrc + k0 + 4);
            union { ushort u[8]; float4 v; } tmp;
            tmp.u[0] = f2bf(v0.x); tmp.u[1] = f2bf(v0.y);
            tmp.u[2] = f2bf(v0.z); tmp.u[3] = f2bf(v0.w);
            tmp.u[4] = f2bf(v1.x); tmp.u[5] = f2bf(v1.y);
            tmp.u[6] = f2bf(v1.z); tmp.u[7] = f2bf(v1.w);
            *(float4*)swz(As, arow, akseg * 16) = tmp.v;
        }
        #pragma unroll
        for (int s = 0; s < 2; ++s) {   // stage B: 128 rows x 64 k bf16 copy
            int j = s * 512 + t;
            int n = j >> 3, kseg = j & 7;
            *(float4*)swz(Bs, n, kseg * 16) =
                *(const float4*)(wcat + (size_t)n * C_ + k0 + kseg * 8);
        }
        __syncthreads();
        #pragma unroll
        for (int ks = 0; ks < 2; ++ks) {
            bf16x8 b = *(const bf16x8*)swz(Bs, wid * 16 + lo, ks * 64 + hi * 16);
            #pragma unroll
            for (int i = 0; i < 4; ++i) {
                bf16x8 a = *(const bf16x8*)swz(As, i * 16 + lo, ks * 64 + hi * 16);
                acc[i] = __builtin_amdgcn_mfma_f32_16x16x32_bf16(a, b, acc[i], 0, 0, 0);
            }
        }
    }

    const int n = wid * 16 + lo;      // 0..127
    if (wid < 4) {
        const float bias = b1[n];
        #pragma unroll
        for (int i = 0; i < 4; ++i)
            #pragma unroll
            for (int r = 0; r < 4; ++r) {
                int pos = bm * 64 + i * 16 + hi * 4 + r;
                hbuf[(size_t)pos * 64 + n] = relu(acc[i][r] + bias);
            }
    } else {
        const float bias = db[n - 64];
        #pragma unroll
        for (int i = 0; i < 4; ++i)
            #pragma unroll
            for (int r = 0; r < 4; ++r) {
                int pos = bm * 64 + i * 16 + hi * 4 + r;
                xact[(size_t)pos * 64 + (n - 64)] = f2bf(qgelu(acc[i][r] + bias));
            }
    }
}

// ---------------- Stage 2: spatial mean + meta2 (commuted past mean) ----------------
__global__ void k_reduce(const float* __restrict__ hbuf,
                         const float* __restrict__ w2, const float* __restrict__ b2,
                         float* __restrict__ prompt)
{
    __shared__ float part[4][EMB_];
    __shared__ float hm[EMB_];
    const int b     = blockIdx.x;
    const int lane  = threadIdx.x & 63;
    const int chunk = threadIdx.x >> 6;
    float acc = 0.f;
    for (int i = chunk; i < HW_; i += 4)
        acc += hbuf[((size_t)b * HW_ + i) * EMB_ + lane];
    part[chunk][lane] = acc;
    __syncthreads();
    if (threadIdx.x < EMB_) {
        float s = part[0][threadIdx.x] + part[1][threadIdx.x]
                + part[2][threadIdx.x] + part[3][threadIdx.x];
        hm[threadIdx.x] = s * (1.f / HW_);
    }
    __syncthreads();
    if (threadIdx.x < EMB_) {
        const int e = threadIdx.x;
        const float* w2r = w2 + (size_t)e * EMB_;
        float a0 = 0.f, a1 = 0.f, a2 = 0.f, a3 = 0.f;
        #pragma unroll
        for (int i = 0; i < EMB_; i += 4) {
            a0 = fmaf(hm[i + 0], w2r[i + 0], a0);
            a1 = fmaf(hm[i + 1], w2r[i + 1], a1);
            a2 = fmaf(hm[i + 2], w2r[i + 2], a2);
            a3 = fmaf(hm[i + 3], w2r[i + 3], a3);
        }
        prompt[b * EMB_ + e] = (a0 + a1) + (a2 + a3) + b2[e];
    }
}

// ---------------- Stage 3: hypernet -> bf16 conv weights [b][tap][dout][din] ----------------
// f = tap*4096 + dout*64 + din  <->  hyper_w row r = (dout*64+din)*9 + tap
__global__ void k_hyper(const float* __restrict__ prompt, const float* __restrict__ layer_emb,
                        const float* __restrict__ hyper_w, const float* __restrict__ hyper_b,
                        ushort* __restrict__ cwb)
{
    __shared__ float fused[B_][EMB_];
    const int tid = threadIdx.x;
    for (int i = tid; i < B_ * EMB_; i += 256) {
        int e = i & (EMB_ - 1);
        fused[i >> 6][e] = layer_emb[e] + prompt[i];
    }
    __syncthreads();

    const int f    = blockIdx.x * 256 + tid;
    const int din  = f & 63;
    const int dout = (f >> 6) & 63;
    const int tap  = f >> 12;
    const int r    = (dout * 64 + din) * 9 + tap;

    float wrow[EMB_];
    const float4* hw4 = (const float4*)(hyper_w + (size_t)r * EMB_);
    #pragma unroll
    for (int i = 0; i < EMB_ / 4; ++i) {
        float4 v = hw4[i];
        wrow[i*4+0] = v.x; wrow[i*4+1] = v.y; wrow[i*4+2] = v.z; wrow[i*4+3] = v.w;
    }
    const float hb = hyper_b[r];

    const int b0 = blockIdx.y * 8;
    for (int b = b0; b < b0 + 8; ++b) {
        float a0 = 0.f, a1 = 0.f, a2 = 0.f, a3 = 0.f;
        #pragma unroll
        for (int i = 0; i < EMB_; i += 4) {
            a0 = fmaf(fused[b][i+0], wrow[i+0], a0);
            a1 = fmaf(fused[b][i+1], wrow[i+1], a1);
            a2 = fmaf(fused[b][i+2], wrow[i+2], a2);
            a3 = fmaf(fused[b][i+3], wrow[i+3], a3);
        }
        cwb[(size_t)b * CWROWS + f] = f2bf((a0 + a1) + (a2 + a3) + hb);
    }
}

// ---------------- Stage 5: MFMA per-sample 3x3 conv + QuickGELU ----------------
// block = (b,h), 8 waves = 2 M-tiles (w) x 4 N-tiles (dout). K = 9 taps x 64 din.
__global__ __launch_bounds__(512)
void k_conv(const ushort* __restrict__ xact, const ushort* __restrict__ cwb,
            ushort* __restrict__ yact)
{
    __shared__ ushort wsl[192 * 64];   // [kw*64+dout][din] swizzled, 24 KB
    __shared__ ushort xs[34 * 64];     // [w+1][din] swizzled (halo+pad), 4.25 KB
    const int t = threadIdx.x;
    const int lane = t & 63;
    const int lo = lane & 15, hi = lane >> 4;
    const int b = blockIdx.x / H_;
    const int h = blockIdx.x % H_;
    const int mtile = (t >> 6) >> 2;   // 0..1
    const int ntile = (t >> 6) & 3;    // 0..3
    const int w0 = mtile * 16;

    f32x4 acc = {};

    for (int kh = 0; kh < 3; ++kh) {
        const int hh = h + kh - 1;
        __syncthreads();
        // stage weight slice for taps kh*3..kh*3+2 (1536 b128 chunks)
        const ushort* wsrc = cwb + (size_t)b * CWROWS + (size_t)kh * 3 * 4096;
        #pragma unroll
        for (int s = 0; s < 3; ++s) {
            int j = s * 512 + t;
            *(float4*)swz(wsl, j >> 3, (j & 7) * 16) = *(const float4*)(wsrc + j * 8);
        }
        // stage x row hh with 1-col halo, zero-padded (34 cols x 64 din)
        if (t < 272) {
            int c = t >> 3, kseg = t & 7;
            int w = c - 1;
            float4 v = make_float4(0.f, 0.f, 0.f, 0.f);
            if (hh >= 0 && hh < H_ && w >= 0 && w < W_)
                v = *(const float4*)(xact + ((size_t)((b * H_ + hh) * W_) + w) * 64 + kseg * 8);
            *(float4*)swz(xs, c, kseg * 16) = v;
        }
        __syncthreads();
        #pragma unroll
        for (int kw = 0; kw < 3; ++kw) {
            #pragma unroll
            for (int ks = 0; ks < 2; ++ks) {
                bf16x8 a  = *(const bf16x8*)swz(xs, w0 + lo + kw, ks * 64 + hi * 16);
                bf16x8 bf = *(const bf16x8*)swz(wsl, kw * 64 + ntile * 16 + lo, ks * 64 + hi * 16);
                acc = __builtin_amdgcn_mfma_f32_16x16x32_bf16(a, bf, acc, 0, 0, 0);
            }
        }
    }

    const int dout = ntile * 16 + lo;
    #pragma unroll
    for (int r = 0; r < 4; ++r) {
        int w = w0 + hi * 4 + r;
        if (w < W_)
            yact[((size_t)((b * H_ + h) * W_) + w) * 64 + dout] = f2bf(qgelu(acc[r]));
    }
}

// ---------------- Stage 6: MFMA GEMM  M=25088 N=768 K=64 ----------------
__global__ __launch_bounds__(512)
void k_up(const ushort* __restrict__ yact, const ushort* __restrict__ wup,
          const float* __restrict__ ub, float* __restrict__ out)
{
    __shared__ ushort As[64 * 64];    //  8 KB
    __shared__ ushort Bs[256 * 64];   // 32 KB
    const int t = threadIdx.x;
    const int wid = t >> 6, lane = t & 63;
    const int lo = lane & 15, hi = lane >> 4;
    const int bm = blockIdx.x;        // 392

    {   // stage A once (yact already bf16): one b128 per thread
        int row = t >> 3, kseg = t & 7;
        *(float4*)swz(As, row, kseg * 16) =
            *(const float4*)(yact + (size_t)(bm * 64 + row) * 64 + kseg * 8);
    }

    for (int nc = 0; nc < 3; ++nc) {
        __syncthreads();
        #pragma unroll
        for (int s = 0; s < 4; ++s) {   // stage B: 256 n-rows x 64 k
            int j = s * 512 + t;
            int n = j >> 3, kseg = j & 7;
            *(float4*)swz(Bs, n, kseg * 16) =
                *(const float4*)(wup + (size_t)(nc * 256 + n) * 64 + kseg * 8);
        }
        __syncthreads();

        f32x4 acc[4][2] = {};
        #pragma unroll
        for (int ks = 0; ks < 2; ++ks) {
            bf16x8 a[4], b[2];
            #pragma unroll
            for (int i = 0; i < 4; ++i)
                a[i] = *(const bf16x8*)swz(As, i * 16 + lo, ks * 64 + hi * 16);
            #pragma unroll
            for (int j = 0; j < 2; ++j)
                b[j] = *(const bf16x8*)swz(Bs, wid * 32 + j * 16 + lo, ks * 64 + hi * 16);
            #pragma unroll
            for (int i = 0; i < 4; ++i)
                #pragma unroll
                for (int j = 0; j < 2; ++j)
                    acc[i][j] = __builtin_amdgcn_mfma_f32_16x16x32_bf16(a[i], b[j], acc[i][j], 0, 0, 0);
        }

        #pragma unroll
        for (int j = 0; j < 2; ++j) {
            const int n = nc * 256 + wid * 32 + j * 16 + lo;
            const float bias = ub[n];
            #pragma unroll
            for (int i = 0; i < 4; ++i)
                #pragma unroll
                for (int r = 0; r < 4; ++r) {
                    int pos = bm * 64 + i * 16 + hi * 4 + r;
                    out[(size_t)pos * C_ + n] = acc[i][j][r] + bias;
                }
        }
    }
}

extern "C" void kernel_launch(void* const* d_in, const int* in_sizes, int n_in,
                              void* d_out, int out_size, void* d_ws, size_t ws_size,
                              hipStream_t stream) {
    const float* x         = (const float*)d_in[0];
    const float* meta_w1   = (const float*)d_in[1];
    const float* meta_b1   = (const float*)d_in[2];
    const float* meta_w2   = (const float*)d_in[3];
    const float* meta_b2   = (const float*)d_in[4];
    const float* layer_emb = (const float*)d_in[5];
    const float* hyper_w   = (const float*)d_in[6];
    const float* hyper_b   = (const float*)d_in[7];
    const float* down_w    = (const float*)d_in[8];
    const float* down_b    = (const float*)d_in[9];
    const float* up_w      = (const float*)d_in[10];
    const float* up_b      = (const float*)d_in[11];
    float* out = (float*)d_out;

    // ws layout (16-B aligned regions). yact (bf16) aliases hbuf: hbuf dead
    // after k_reduce, k_conv writes yact afterwards (stream-serialized).
    char* p = (char*)d_ws;
    float*  hbuf   = (float*)p;            p += (size_t)NPOS * 64 * 4;
    ushort* yact   = (ushort*)hbuf;        // alias
    ushort* xact   = (ushort*)p;           p += (size_t)NPOS * 64 * 2;
    float*  prompt = (float*)p;            p += (size_t)B_ * EMB_ * 4;
    ushort* cwb    = (ushort*)p;           p += (size_t)B_ * CWROWS * 2;
    ushort* wcat   = (ushort*)p;           p += (size_t)128 * C_ * 2;
    ushort* wup    = (ushort*)p;

    k_cvt<<<144, 256, 0, stream>>>(meta_w1, down_w, up_w, wcat, wup);
    k_gemm_md<<<NPOS / 64, 512, 0, stream>>>(x, wcat, meta_b1, down_b, hbuf, xact);
    k_reduce<<<B_, 256, 0, stream>>>(hbuf, meta_w2, meta_b2, prompt);
    dim3 hgrid(CWROWS / 256, B_ / 8);
    k_hyper<<<hgrid, 256, 0, stream>>>(prompt, layer_emb, hyper_w, hyper_b, cwb);
    k_conv<<<B_ * H_, 512, 0, stream>>>(xact, cwb, yact);
    k_up<<<NPOS / 64, 512, 0, stream>>>(yact, wup, up_b, out);
}

// Round 7
// 69.719 us; speedup vs baseline: 4.8579x; 1.5816x over previous
//
#include <hip/hip_runtime.h>
#include <math.h>

#define B_    32
#define H_    28
#define W_    28
#define C_    768
#define D_    64
#define EMB_  64
#define HW_   (H_ * W_)
#define NPOS  (B_ * HW_)          // 25088
#define CWROWS (D_ * D_ * 9)      // 36864

typedef __attribute__((ext_vector_type(8))) short bf16x8;
typedef __attribute__((ext_vector_type(4))) float f32x4;

__device__ __forceinline__ float qgelu(float v) {
    return v / (1.f + __expf(-1.702f * v));
}
__device__ __forceinline__ float relu(float v) { return fmaxf(v, 0.f); }

// fp32 -> bf16 RTNE
__device__ __forceinline__ ushort f2bf(float f) {
    union { float f; unsigned u; } v; v.f = f;
    return (ushort)((v.u + 0x7fffu + ((v.u >> 16) & 1u)) >> 16);
}

// XOR-swizzled LDS tile address: rows are 128 B (64 bf16); byte offset within
// row is kbyte ^ ((row&7)<<4) -> b128 reads across 16 rows are <=2-way (free).
__device__ __forceinline__ void* swz(void* base, int row, int kbyte) {
    return (void*)((char*)base + row * 128 + (kbyte ^ ((row & 7) << 4)));
}

// ---------------- Stage 0: weight convert fp32 -> bf16 ----------------
__global__ void k_cvt(const float* __restrict__ w1, const float* __restrict__ dw,
                      const float* __restrict__ uw,
                      ushort* __restrict__ wcat, ushort* __restrict__ wup)
{
    const int f = (blockIdx.x * 256 + threadIdx.x) * 4;   // 147456 total
    const float* src;
    ushort* dst;
    if (f < 49152)      { src = w1 + f;           dst = wcat + f; }
    else if (f < 98304) { src = dw + (f - 49152); dst = wcat + f; }
    else                { src = uw + (f - 98304); dst = wup + (f - 98304); }
    float4 v = *(const float4*)src;
    union { ushort u[4]; uint2 p; } o;
    o.u[0] = f2bf(v.x); o.u[1] = f2bf(v.y); o.u[2] = f2bf(v.z); o.u[3] = f2bf(v.w);
    *(uint2*)dst = o.p;
}

// ---------------- Stage 1+4: MFMA GEMM  M=25088 N=128 K=768 ----------------
// waves 0-3 -> hbuf f32 (relu), waves 4-7 -> xact bf16 (qgelu)
__global__ __launch_bounds__(512)
void k_gemm_md(const float* __restrict__ x, const ushort* __restrict__ wcat,
               const float* __restrict__ b1, const float* __restrict__ db,
               float* __restrict__ hbuf, ushort* __restrict__ xact)
{
    __shared__ ushort As[64 * 64];    //  8 KB, [m][k] swizzled
    __shared__ ushort Bs[128 * 64];   // 16 KB, [n][k] swizzled
    const int t = threadIdx.x;
    const int wid = t >> 6, lane = t & 63;
    const int lo = lane & 15, hi = lane >> 4;
    const int bm = blockIdx.x;        // 392

    f32x4 acc[4] = {};

    const int arow = t >> 3, akseg = t & 7;
    const float* asrc = x + (size_t)(bm * 64 + arow) * C_ + akseg * 8;

    for (int k0 = 0; k0 < C_; k0 += 64) {
        __syncthreads();
        {   // stage A: 64 rows x 64 k, fp32->bf16, one b128 per thread
            float4 v0 = *(const float4*)(asrc + k0);
            float4 v1 = *(const float4*)(asrc + k0 + 4);
            union { ushort u[8]; float4 v; } tmp;
            tmp.u[0] = f2bf(v0.x); tmp.u[1] = f2bf(v0.y);
            tmp.u[2] = f2bf(v0.z); tmp.u[3] = f2bf(v0.w);
            tmp.u[4] = f2bf(v1.x); tmp.u[5] = f2bf(v1.y);
            tmp.u[6] = f2bf(v1.z); tmp.u[7] = f2bf(v1.w);
            *(float4*)swz(As, arow, akseg * 16) = tmp.v;
        }
        #pragma unroll
        for (int s = 0; s < 2; ++s) {   // stage B: 128 rows x 64 k bf16 copy
            int j = s * 512 + t;
            int n = j >> 3, kseg = j & 7;
            *(float4*)swz(Bs, n, kseg * 16) =
                *(const float4*)(wcat + (size_t)n * C_ + k0 + kseg * 8);
        }
        __syncthreads();
        #pragma unroll
        for (int ks = 0; ks < 2; ++ks) {
            bf16x8 b = *(const bf16x8*)swz(Bs, wid * 16 + lo, ks * 64 + hi * 16);
            #pragma unroll
            for (int i = 0; i < 4; ++i) {
                bf16x8 a = *(const bf16x8*)swz(As, i * 16 + lo, ks * 64 + hi * 16);
                acc[i] = __builtin_amdgcn_mfma_f32_16x16x32_bf16(a, b, acc[i], 0, 0, 0);
            }
        }
    }

    const int n = wid * 16 + lo;      // 0..127
    if (wid < 4) {
        const float bias = b1[n];
        #pragma unroll
        for (int i = 0; i < 4; ++i)
            #pragma unroll
            for (int r = 0; r < 4; ++r) {
                int pos = bm * 64 + i * 16 + hi * 4 + r;
                hbuf[(size_t)pos * 64 + n] = relu(acc[i][r] + bias);
            }
    } else {
        const float bias = db[n - 64];
        #pragma unroll
        for (int i = 0; i < 4; ++i)
            #pragma unroll
            for (int r = 0; r < 4; ++r) {
                int pos = bm * 64 + i * 16 + hi * 4 + r;
                xact[(size_t)pos * 64 + (n - 64)] = f2bf(qgelu(acc[i][r] + bias));
            }
    }
}

// ---------------- Stage 2a: partial spatial sum (b, quarter) ----------------
// partial[(b*4+q)*64 + e] = sum over positions q*196..q*196+195 of hbuf[b][.][e]
__global__ void k_reduce1(const float* __restrict__ hbuf, float* __restrict__ partial)
{
    __shared__ float part[16][EMB_];
    const int b = blockIdx.x, q = blockIdx.y;
    const int tid = threadIdx.x;
    const int e4 = tid & 15, pc = tid >> 4;

    const float* base = hbuf + ((size_t)b * HW_ + q * 196) * 64 + e4 * 4;
    float4 acc = make_float4(0.f, 0.f, 0.f, 0.f);
    for (int i = pc; i < 196; i += 16) {
        float4 v = *(const float4*)(base + (size_t)i * 64);
        acc.x += v.x; acc.y += v.y; acc.z += v.z; acc.w += v.w;
    }
    part[pc][e4 * 4 + 0] = acc.x;
    part[pc][e4 * 4 + 1] = acc.y;
    part[pc][e4 * 4 + 2] = acc.z;
    part[pc][e4 * 4 + 3] = acc.w;
    __syncthreads();
    if (tid < EMB_) {
        float s = 0.f;
        #pragma unroll
        for (int c = 0; c < 16; ++c) s += part[c][tid];
        partial[(size_t)(b * 4 + q) * EMB_ + tid] = s;
    }
}

// ---------------- Stage 2b: final mean + meta2 (commuted past mean) ----------------
__global__ void k_reduce2(const float* __restrict__ partial,
                          const float* __restrict__ w2, const float* __restrict__ b2,
                          float* __restrict__ prompt)
{
    __shared__ float hm[EMB_];
    const int b = blockIdx.x;
    const int e = threadIdx.x;    // 64 threads = 1 wave
    float s = partial[(size_t)(b * 4 + 0) * EMB_ + e]
            + partial[(size_t)(b * 4 + 1) * EMB_ + e]
            + partial[(size_t)(b * 4 + 2) * EMB_ + e]
            + partial[(size_t)(b * 4 + 3) * EMB_ + e];
    hm[e] = s * (1.f / HW_);
    __syncthreads();
    const float4* w2r = (const float4*)(w2 + (size_t)e * EMB_);
    const float4* hm4 = (const float4*)hm;
    float a0 = 0.f, a1 = 0.f, a2 = 0.f, a3 = 0.f;
    #pragma unroll
    for (int i = 0; i < EMB_ / 4; ++i) {
        float4 h = hm4[i], w = w2r[i];
        a0 = fmaf(h.x, w.x, a0); a1 = fmaf(h.y, w.y, a1);
        a2 = fmaf(h.z, w.z, a2); a3 = fmaf(h.w, w.w, a3);
    }
    prompt[b * EMB_ + e] = (a0 + a1) + (a2 + a3) + b2[e];
}

// ---------------- Stage 3: hypernet -> bf16 conv weights [b][tap][dout][din] ----------------
// f = tap*4096 + dout*64 + din  <->  hyper_w row r = (dout*64+din)*9 + tap
__global__ void k_hyper(const float* __restrict__ prompt, const float* __restrict__ layer_emb,
                        const float* __restrict__ hyper_w, const float* __restrict__ hyper_b,
                        ushort* __restrict__ cwb)
{
    __shared__ float fused[B_][EMB_];
    const int tid = threadIdx.x;
    for (int i = tid; i < B_ * EMB_; i += 256) {
        int e = i & (EMB_ - 1);
        fused[i >> 6][e] = layer_emb[e] + prompt[i];
    }
    __syncthreads();

    const int f    = blockIdx.x * 256 + tid;
    const int din  = f & 63;
    const int dout = (f >> 6) & 63;
    const int tap  = f >> 12;
    const int r    = (dout * 64 + din) * 9 + tap;

    float wrow[EMB_];
    const float4* hw4 = (const float4*)(hyper_w + (size_t)r * EMB_);
    #pragma unroll
    for (int i = 0; i < EMB_ / 4; ++i) {
        float4 v = hw4[i];
        wrow[i*4+0] = v.x; wrow[i*4+1] = v.y; wrow[i*4+2] = v.z; wrow[i*4+3] = v.w;
    }
    const float hb = hyper_b[r];

    const int b0 = blockIdx.y * 8;
    for (int b = b0; b < b0 + 8; ++b) {
        float a0 = 0.f, a1 = 0.f, a2 = 0.f, a3 = 0.f;
        #pragma unroll
        for (int i = 0; i < EMB_; i += 4) {
            a0 = fmaf(fused[b][i+0], wrow[i+0], a0);
            a1 = fmaf(fused[b][i+1], wrow[i+1], a1);
            a2 = fmaf(fused[b][i+2], wrow[i+2], a2);
            a3 = fmaf(fused[b][i+3], wrow[i+3], a3);
        }
        cwb[(size_t)b * CWROWS + f] = f2bf((a0 + a1) + (a2 + a3) + hb);
    }
}

// ---------------- Stage 5: MFMA per-sample 3x3 conv + QuickGELU ----------------
// block = (b,h), 8 waves = 2 M-tiles (w) x 4 N-tiles (dout). K = 9 taps x 64 din.
__global__ __launch_bounds__(512)
void k_conv(const ushort* __restrict__ xact, const ushort* __restrict__ cwb,
            ushort* __restrict__ yact)
{
    __shared__ ushort wsl[192 * 64];   // [kw*64+dout][din] swizzled, 24 KB
    __shared__ ushort xs[34 * 64];     // [w+1][din] swizzled (halo+pad), 4.25 KB
    const int t = threadIdx.x;
    const int lane = t & 63;
    const int lo = lane & 15, hi = lane >> 4;
    const int b = blockIdx.x / H_;
    const int h = blockIdx.x % H_;
    const int mtile = (t >> 6) >> 2;   // 0..1
    const int ntile = (t >> 6) & 3;    // 0..3
    const int w0 = mtile * 16;

    f32x4 acc = {};

    for (int kh = 0; kh < 3; ++kh) {
        const int hh = h + kh - 1;
        __syncthreads();
        // stage weight slice for taps kh*3..kh*3+2 (1536 b128 chunks)
        const ushort* wsrc = cwb + (size_t)b * CWROWS + (size_t)kh * 3 * 4096;
        #pragma unroll
        for (int s = 0; s < 3; ++s) {
            int j = s * 512 + t;
            *(float4*)swz(wsl, j >> 3, (j & 7) * 16) = *(const float4*)(wsrc + j * 8);
        }
        // stage x row hh with 1-col halo, zero-padded (34 cols x 64 din)
        if (t < 272) {
            int c = t >> 3, kseg = t & 7;
            int w = c - 1;
            float4 v = make_float4(0.f, 0.f, 0.f, 0.f);
            if (hh >= 0 && hh < H_ && w >= 0 && w < W_)
                v = *(const float4*)(xact + ((size_t)((b * H_ + hh) * W_) + w) * 64 + kseg * 8);
            *(float4*)swz(xs, c, kseg * 16) = v;
        }
        __syncthreads();
        #pragma unroll
        for (int kw = 0; kw < 3; ++kw) {
            #pragma unroll
            for (int ks = 0; ks < 2; ++ks) {
                bf16x8 a  = *(const bf16x8*)swz(xs, w0 + lo + kw, ks * 64 + hi * 16);
                bf16x8 bf = *(const bf16x8*)swz(wsl, kw * 64 + ntile * 16 + lo, ks * 64 + hi * 16);
                acc = __builtin_amdgcn_mfma_f32_16x16x32_bf16(a, bf, acc, 0, 0, 0);
            }
        }
    }

    const int dout = ntile * 16 + lo;
    #pragma unroll
    for (int r = 0; r < 4; ++r) {
        int w = w0 + hi * 4 + r;
        if (w < W_)
            yact[((size_t)((b * H_ + h) * W_) + w) * 64 + dout] = f2bf(qgelu(acc[r]));
    }
}

// ---------------- Stage 6: MFMA GEMM  M=25088 N=768 K=64 ----------------
__global__ __launch_bounds__(512)
void k_up(const ushort* __restrict__ yact, const ushort* __restrict__ wup,
          const float* __restrict__ ub, float* __restrict__ out)
{
    __shared__ ushort As[64 * 64];    //  8 KB
    __shared__ ushort Bs[256 * 64];   // 32 KB
    const int t = threadIdx.x;
    const int wid = t >> 6, lane = t & 63;
    const int lo = lane & 15, hi = lane >> 4;
    const int bm = blockIdx.x;        // 392

    {   // stage A once (yact already bf16): one b128 per thread
        int row = t >> 3, kseg = t & 7;
        *(float4*)swz(As, row, kseg * 16) =
            *(const float4*)(yact + (size_t)(bm * 64 + row) * 64 + kseg * 8);
    }

    for (int nc = 0; nc < 3; ++nc) {
        __syncthreads();
        #pragma unroll
        for (int s = 0; s < 4; ++s) {   // stage B: 256 n-rows x 64 k
            int j = s * 512 + t;
            int n = j >> 3, kseg = j & 7;
            *(float4*)swz(Bs, n, kseg * 16) =
                *(const float4*)(wup + (size_t)(nc * 256 + n) * 64 + kseg * 8);
        }
        __syncthreads();

        f32x4 acc[4][2] = {};
        #pragma unroll
        for (int ks = 0; ks < 2; ++ks) {
            bf16x8 a[4], b[2];
            #pragma unroll
            for (int i = 0; i < 4; ++i)
                a[i] = *(const bf16x8*)swz(As, i * 16 + lo, ks * 64 + hi * 16);
            #pragma unroll
            for (int j = 0; j < 2; ++j)
                b[j] = *(const bf16x8*)swz(Bs, wid * 32 + j * 16 + lo, ks * 64 + hi * 16);
            #pragma unroll
            for (int i = 0; i < 4; ++i)
                #pragma unroll
                for (int j = 0; j < 2; ++j)
                    acc[i][j] = __builtin_amdgcn_mfma_f32_16x16x32_bf16(a[i], b[j], acc[i][j], 0, 0, 0);
        }

        #pragma unroll
        for (int j = 0; j < 2; ++j) {
            const int n = nc * 256 + wid * 32 + j * 16 + lo;
            const float bias = ub[n];
            #pragma unroll
            for (int i = 0; i < 4; ++i)
                #pragma unroll
                for (int r = 0; r < 4; ++r) {
                    int pos = bm * 64 + i * 16 + hi * 4 + r;
                    out[(size_t)pos * C_ + n] = acc[i][j][r] + bias;
                }
        }
    }
}

extern "C" void kernel_launch(void* const* d_in, const int* in_sizes, int n_in,
                              void* d_out, int out_size, void* d_ws, size_t ws_size,
                              hipStream_t stream) {
    const float* x         = (const float*)d_in[0];
    const float* meta_w1   = (const float*)d_in[1];
    const float* meta_b1   = (const float*)d_in[2];
    const float* meta_w2   = (const float*)d_in[3];
    const float* meta_b2   = (const float*)d_in[4];
    const float* layer_emb = (const float*)d_in[5];
    const float* hyper_w   = (const float*)d_in[6];
    const float* hyper_b   = (const float*)d_in[7];
    const float* down_w    = (const float*)d_in[8];
    const float* down_b    = (const float*)d_in[9];
    const float* up_w      = (const float*)d_in[10];
    const float* up_b      = (const float*)d_in[11];
    float* out = (float*)d_out;

    // ws layout (16-B aligned regions). yact (bf16) aliases hbuf: hbuf dead
    // after k_reduce1, k_conv writes yact afterwards (stream-serialized).
    char* p = (char*)d_ws;
    float*  hbuf    = (float*)p;           p += (size_t)NPOS * 64 * 4;
    ushort* yact    = (ushort*)hbuf;       // alias
    ushort* xact    = (ushort*)p;          p += (size_t)NPOS * 64 * 2;
    float*  prompt  = (float*)p;           p += (size_t)B_ * EMB_ * 4;
    float*  partial = (float*)p;           p += (size_t)B_ * 4 * EMB_ * 4;
    ushort* cwb     = (ushort*)p;          p += (size_t)B_ * CWROWS * 2;
    ushort* wcat    = (ushort*)p;          p += (size_t)128 * C_ * 2;
    ushort* wup     = (ushort*)p;

    k_cvt<<<144, 256, 0, stream>>>(meta_w1, down_w, up_w, wcat, wup);
    k_gemm_md<<<NPOS / 64, 512, 0, stream>>>(x, wcat, meta_b1, down_b, hbuf, xact);
    k_reduce1<<<dim3(B_, 4), 256, 0, stream>>>(hbuf, partial);
    k_reduce2<<<B_, 64, 0, stream>>>(partial, meta_w2, meta_b2, prompt);
    dim3 hgrid(CWROWS / 256, B_ / 8);
    k_hyper<<<hgrid, 256, 0, stream>>>(prompt, layer_emb, hyper_w, hyper_b, cwb);
    k_conv<<<B_ * H_, 512, 0, stream>>>(xact, cwb, yact);
    k_up<<<NPOS / 64, 512, 0, stream>>>(yact, wup, up_b, out);
}